// Round 2
// baseline (323.276 us; speedup 1.0000x reference)
//
#include <hip/hip_runtime.h>
#include <hip/hip_bf16.h>

#define BATCH 16
#define CIN   512
#define HW    3136
#define CM    512
#define CN    128

typedef short short8 __attribute__((ext_vector_type(8)));
typedef float f32x4  __attribute__((ext_vector_type(4)));

#define MFMA(a,b,c) __builtin_amdgcn_mfma_f32_16x16x32_bf16((a),(b),(c),0,0,0)

// convert 8 consecutive fp32 -> 8 bf16, store as one 16B chunk (LDS or global)
__device__ __forceinline__ void cvt_store8(__bf16* dst, const float* src) {
  const f32x4 a = *(const f32x4*)src;
  const f32x4 b = *(const f32x4*)(src + 4);
  __attribute__((aligned(16))) __bf16 t[8];
  t[0] = (__bf16)a[0]; t[1] = (__bf16)a[1]; t[2] = (__bf16)a[2]; t[3] = (__bf16)a[3];
  t[4] = (__bf16)b[0]; t[5] = (__bf16)b[1]; t[6] = (__bf16)b[2]; t[7] = (__bf16)b[3];
  *(uint4*)dst = *(uint4*)t;
}

// same, from two f32x4 by value (keeps sources in registers)
__device__ __forceinline__ void cvt_store8v(__bf16* dst, f32x4 a, f32x4 b) {
  __attribute__((aligned(16))) __bf16 t[8];
  t[0] = (__bf16)a[0]; t[1] = (__bf16)a[1]; t[2] = (__bf16)a[2]; t[3] = (__bf16)a[3];
  t[4] = (__bf16)b[0]; t[5] = (__bf16)b[1]; t[6] = (__bf16)b[2]; t[7] = (__bf16)b[3];
  *(uint4*)dst = *(uint4*)t;
}

// ---------------------------------------------------------------------------
// Kernel 0: pre-convert (wB|wV) fp32 -> bf16 in MFMA-fragment order.
// Chunk gid = st*2048 + w*512 + mi*128 + kk*64 + lane  (16 B per chunk):
//   holds W[w*64+mi*16+(lane&15)][st*64+kk*32+(lane>>4)*8 .. +8]
// so conv wave w's fragment load (st,mi,kk) is 64 lanes x consecutive 16 B.
// ---------------------------------------------------------------------------
__global__ __launch_bounds__(256) void prep_w_kernel(
    const float* __restrict__ wB, const float* __restrict__ wV,
    __bf16* __restrict__ Wimg)
{
  const int gid  = blockIdx.x * 256 + threadIdx.x;   // 0..16383
  const int lane = gid & 63;
  const int kk   = (gid >> 6) & 1;
  const int mi   = (gid >> 7) & 3;
  const int w    = (gid >> 9) & 3;
  const int st   = (gid >> 11) & 7;
  const int row  = w*64 + mi*16 + (lane & 15);
  const int col  = st*64 + kk*32 + (lane >> 4)*8;
  const float* src = (row < 128) ? (wB + (size_t)row * CIN)
                                 : (wV + (size_t)(row - 128) * CIN);
  cvt_store8(Wimg + (size_t)gid * 8, src + col);
}

// ---------------------------------------------------------------------------
// Kernel 1: conv (wB|wV) @ x + bias, fused V-softmax (transposed attVT out)
// and fused B-softmax row sums (atomics).
// W fragments loaded straight to registers from fragment-ordered Wimg (L2-hot)
// -> no Wt in LDS. Xt double-buffered -> ONE barrier per K-step. X prefetch is
// a full iteration ahead (issued at st, consumed at st+1).
// ---------------------------------------------------------------------------
__global__ __launch_bounds__(256) void conv_bv_kernel(
    const float* __restrict__ x,
    const __bf16* __restrict__ Wimg,
    const float* __restrict__ bB, const float* __restrict__ bV,
    __bf16* __restrict__ BVB, __bf16* __restrict__ attVT,
    float* __restrict__ bsum)
{
  const int s0  = blockIdx.x * 64;
  const int b   = blockIdx.y;
  const int tid = threadIdx.x;
  const int lane = tid & 63, w = tid >> 6;
  const int l15  = lane & 15, q = lane >> 4;

  __shared__ __attribute__((aligned(16))) __bf16 Xt[2][64*72]; // 18432 B
  __bf16* T = (__bf16*)Xt;   // epilogue alias [64][136] = 17408 B
  __shared__ float Vm[2][64];
  __shared__ float Vs[2][64];

  f32x4 acc[4][4] = {};
  const float* xb = x + (size_t)b*CIN*HW + s0;
  const int colg = tid & 7;               // s-octet
  const int cl = 2*(tid >> 3);            // even c_local (pair cl, cl+1)
  const int xoff = ((cl >> 3) ^ colg)*8 + (cl & 7);

  const char* wbase = (const char*)Wimg + (size_t)w*8192 + (size_t)lane*16;

  // W fragment regs for the current step (loaded one step ahead)
  short8 wf[8];
#define WLOAD(ST) do { const char* wp_ = wbase + (ST)*32768; \
    wf[0]=*(const short8*)(wp_+0);    wf[1]=*(const short8*)(wp_+1024); \
    wf[2]=*(const short8*)(wp_+2048); wf[3]=*(const short8*)(wp_+3072); \
    wf[4]=*(const short8*)(wp_+4096); wf[5]=*(const short8*)(wp_+5120); \
    wf[6]=*(const short8*)(wp_+6144); wf[7]=*(const short8*)(wp_+7168); } while(0)

  // X prefetch double buffer: pf[m&1] holds x-cols for step m
  f32x4 pf[2][4];
#define XLOAD(PB, K0) do { \
    const float* r0_ = xb + (size_t)((K0) + cl)*HW + colg*8; \
    const float* r1_ = r0_ + HW; \
    pf[PB][0] = *(const f32x4*)r0_; pf[PB][1] = *(const f32x4*)(r0_ + 4); \
    pf[PB][2] = *(const f32x4*)r1_; pf[PB][3] = *(const f32x4*)(r1_ + 4); } while(0)

#define XWRITE(BUF, PB) do { \
    _Pragma("unroll") \
    for (int j = 0; j < 8; ++j) { \
      int s_ = colg*8 + j; \
      union { __bf16 h[2]; unsigned int u; } pv_; \
      pv_.h[0] = (__bf16)pf[PB][j>>2][j&3]; \
      pv_.h[1] = (__bf16)pf[PB][2 + (j>>2)][j&3]; \
      *(unsigned int*)&Xt[BUF][s_*72 + xoff] = pv_.u; \
    } } while(0)

  // prologue: pf(0), W(0), pf(1) in flight; write Xt[0]
  XLOAD(0, 0);
  WLOAD(0);
  XLOAD(1, 64);
  XWRITE(0, 0);
  __syncthreads();

  #pragma unroll
  for (int st = 0; st < 8; ++st) {
    const int cur = st & 1;
    // kk = 0 fragment reads + MFMA (covers the stores/loads issued below)
    short8 xf0[4];
    #pragma unroll
    for (int si = 0; si < 4; ++si) {
      int s = si*16 + l15;
      int oct = q ^ (si*2 + (l15 >> 3));
      xf0[si] = *(short8*)&Xt[cur][s*72 + oct*8];
    }
    #pragma unroll
    for (int mi = 0; mi < 4; ++mi)
      #pragma unroll
      for (int si = 0; si < 4; ++si)
        acc[mi][si] = MFMA(wf[mi*2], xf0[si], acc[mi][si]);

    if (st < 7) XWRITE(cur ^ 1, (st + 1) & 1);   // stage next tile
    if (st < 6) XLOAD(st & 1, (st + 2) * 64);     // prefetch tile after next

    // kk = 1
    short8 xf1[4];
    #pragma unroll
    for (int si = 0; si < 4; ++si) {
      int s = si*16 + l15;
      int oct = (4 + q) ^ (si*2 + (l15 >> 3));
      xf1[si] = *(short8*)&Xt[cur][s*72 + oct*8];
    }
    #pragma unroll
    for (int mi = 0; mi < 4; ++mi)
      #pragma unroll
      for (int si = 0; si < 4; ++si)
        acc[mi][si] = MFMA(wf[mi*2+1], xf1[si], acc[mi][si]);

    if (st < 7) WLOAD(st + 1);  // refill W regs for next step (after last use)
    __syncthreads();
  }
#undef WLOAD
#undef XLOAD
#undef XWRITE

  float bias[4][4];
  #pragma unroll
  for (int mi = 0; mi < 4; ++mi)
    #pragma unroll
    for (int r = 0; r < 4; ++r) {
      int nch = w*64 + mi*16 + q*4 + r;
      bias[mi][r] = (nch < CN) ? bB[nch] : bV[nch - CN];
    }

  if (w < 2) {
    // B half: write raw bf16 rows + accumulate per-n sum of exp
    const size_t outb = (size_t)b * CN * HW;
    float psum[4][4] = {};
    #pragma unroll
    for (int mi = 0; mi < 4; ++mi)
      #pragma unroll
      for (int si = 0; si < 4; ++si) {
        int s = s0 + si*16 + l15;
        #pragma unroll
        for (int r = 0; r < 4; ++r) {
          int nch = w*64 + mi*16 + q*4 + r;
          __bf16 bv = (__bf16)(acc[mi][si][r] + bias[mi][r]);
          BVB[outb + (size_t)nch*HW + s] = bv;
          psum[mi][r] += __expf((float)bv);
        }
      }
    #pragma unroll
    for (int mi = 0; mi < 4; ++mi)
      #pragma unroll
      for (int r = 0; r < 4; ++r) {
        float v = psum[mi][r];
        v += __shfl_xor(v, 1); v += __shfl_xor(v, 2);
        v += __shfl_xor(v, 4); v += __shfl_xor(v, 8);
        if (l15 == 0) {
          int nch = w*64 + mi*16 + q*4 + r;
          atomicAdd(&bsum[b*CN + nch], v);
        }
      }
  } else {
    // V half: per-s max over its 128 V channels
    #pragma unroll
    for (int si = 0; si < 4; ++si) {
      float m = -1e30f;
      #pragma unroll
      for (int mi = 0; mi < 4; ++mi)
        #pragma unroll
        for (int r = 0; r < 4; ++r)
          m = fmaxf(m, acc[mi][si][r] + bias[mi][r]);
      m = fmaxf(m, __shfl_xor(m, 16));
      m = fmaxf(m, __shfl_xor(m, 32));
      if (q == 0) Vm[w-2][si*16 + l15] = m;
    }
  }
  __syncthreads();
  if (w >= 2) {
    #pragma unroll
    for (int si = 0; si < 4; ++si) {
      int idx = si*16 + l15;
      float ms = fmaxf(Vm[0][idx], Vm[1][idx]);
      float ssum = 0.f;
      #pragma unroll
      for (int mi = 0; mi < 4; ++mi)
        #pragma unroll
        for (int r = 0; r < 4; ++r) {
          float e = __expf(acc[mi][si][r] + bias[mi][r] - ms);
          acc[mi][si][r] = e;
          ssum += e;
        }
      ssum += __shfl_xor(ssum, 16);
      ssum += __shfl_xor(ssum, 32);
      if (q == 0) Vs[w-2][idx] = ssum;
    }
  }
  __syncthreads();
  if (w >= 2) {
    #pragma unroll
    for (int si = 0; si < 4; ++si) {
      int idx = si*16 + l15;
      float inv = 1.0f / (Vs[0][idx] + Vs[1][idx]);
      #pragma unroll
      for (int mi = 0; mi < 4; ++mi)
        #pragma unroll
        for (int r = 0; r < 4; ++r) {
          int j = (w-2)*64 + mi*16 + q*4 + r;
          T[idx*136 + j] = (__bf16)(acc[mi][si][r] * inv);
        }
    }
  }
  __syncthreads();
  __bf16* dst = attVT + ((size_t)b*HW + s0)*CN;
  #pragma unroll
  for (int k = 0; k < 4; ++k) {
    int chunk = tid + 256*k;
    int row = chunk >> 4, oct = chunk & 15;
    *(uint4*)&dst[(size_t)row*CN + oct*8] = *(uint4*)&T[row*136 + oct*8];
  }
}

// ---------------------------------------------------------------------------
// Kernel 2: H[b][c][n] += sum_s x[b][c][s] * (exp(BVB[n][s]) / bsum[n])
// tile 64c x 128n (896 blocks), split-K=7, one-step-ahead register prefetch
// ---------------------------------------------------------------------------
__global__ __launch_bounds__(256) void h_gemm_kernel(
    const float* __restrict__ x, const __bf16* __restrict__ BVB,
    const float* __restrict__ bsum, float* __restrict__ H)
{
  const int c0 = blockIdx.x * 64, b = blockIdx.y, kc = blockIdx.z;
  const int tid = threadIdx.x, lane = tid & 63, w = tid >> 6;
  const int l15 = lane & 15, q = lane >> 4;

  __shared__ __attribute__((aligned(16))) __bf16 At[64*72];   // x tile [c][s]
  __shared__ __attribute__((aligned(16))) __bf16 Bt[128*72];  // attB tile [n][s]
  f32x4 acc[4][2] = {};

  const float* xb = x + ((size_t)b*CIN + c0)*HW;
  const __bf16* ab = BVB + (size_t)b*CN*HW;
  const float* bsb = bsum + b*CN;
  const int colg = tid & 7, row0 = tid >> 3;

  float irow[4];
  #pragma unroll
  for (int p = 0; p < 4; ++p) irow[p] = 1.0f / bsb[row0 + 32*p];

  f32x4 px[2][2];
  uint4 pB[4];
#define HLOAD(K0) do { \
    _Pragma("unroll") \
    for (int p = 0; p < 2; ++p) { \
      const float* s_ = xb + (size_t)(row0 + 32*p)*HW + (K0) + colg*8; \
      px[p][0] = *(const f32x4*)s_; px[p][1] = *(const f32x4*)(s_ + 4); \
    } \
    _Pragma("unroll") \
    for (int p = 0; p < 4; ++p) \
      pB[p] = *(const uint4*)(ab + (size_t)(row0 + 32*p)*HW + (K0) + colg*8); \
  } while(0)

  const int kbase = kc * 448;
  HLOAD(kbase);

  for (int ki = 0; ki < 7; ++ki) {
    // consume prefetched tiles into LDS
    #pragma unroll
    for (int p = 0; p < 2; ++p)
      cvt_store8v(&At[(row0 + 32*p)*72 + colg*8], px[p][0], px[p][1]);
    #pragma unroll
    for (int p = 0; p < 4; ++p) {
      const __bf16* v = (const __bf16*)&pB[p];
      __attribute__((aligned(16))) __bf16 t[8];
      #pragma unroll
      for (int j = 0; j < 8; ++j)
        t[j] = (__bf16)(__expf((float)v[j]) * irow[p]);
      *(uint4*)&Bt[(row0 + 32*p)*72 + colg*8] = *(uint4*)t;
    }
    if (ki < 6) HLOAD(kbase + (ki + 1)*64);
    __syncthreads();
    #pragma unroll
    for (int kk = 0; kk < 2; ++kk) {
      short8 a[4], bb[2];
      #pragma unroll
      for (int mi = 0; mi < 4; ++mi)
        a[mi] = *(short8*)&At[(mi*16 + l15)*72 + kk*32 + q*8];
      #pragma unroll
      for (int ni = 0; ni < 2; ++ni)
        bb[ni] = *(short8*)&Bt[(w*32 + ni*16 + l15)*72 + kk*32 + q*8];
      #pragma unroll
      for (int mi = 0; mi < 4; ++mi)
        #pragma unroll
        for (int ni = 0; ni < 2; ++ni)
          acc[mi][ni] = MFMA(a[mi], bb[ni], acc[mi][ni]);
    }
    __syncthreads();
  }
#undef HLOAD

  float* Hb = H + (size_t)b*CIN*CN;
  #pragma unroll
  for (int mi = 0; mi < 4; ++mi)
    #pragma unroll
    for (int ni = 0; ni < 2; ++ni)
      #pragma unroll
      for (int r = 0; r < 4; ++r) {
        int c = c0 + mi*16 + q*4 + r;
        int n = w*32 + ni*16 + l15;
        atomicAdd(&Hb[c*CN + n], acc[mi][ni][r]);
      }
}

// ---------------------------------------------------------------------------
// Kernel 3: G[b] = wA @ H[b] + bA  (M=512 in 64-tiles, N=128, K=512) -> bf16
// ---------------------------------------------------------------------------
__global__ __launch_bounds__(256) void g_gemm_kernel(
    const float* __restrict__ wA, const float* __restrict__ bA,
    const float* __restrict__ H, __bf16* __restrict__ G)
{
  const int m0 = blockIdx.x * 64, b = blockIdx.y;
  const int tid = threadIdx.x, lane = tid & 63, w = tid >> 6;
  const int l15 = lane & 15, q = lane >> 4;

  __shared__ __attribute__((aligned(16))) __bf16 At[64*72];
  __shared__ __attribute__((aligned(16))) __bf16 Bt[128*72];
  f32x4 acc[4][2] = {};

  const float* Hb = H + (size_t)b*CIN*CN;
  const int colg = tid & 7, row0 = tid >> 3;
  const int nn = tid & 127, gh = tid >> 7;

  for (int k0 = 0; k0 < CIN; k0 += 64) {
    #pragma unroll
    for (int p = 0; p < 2; ++p) {
      int row = row0 + 32*p;
      cvt_store8(&At[row*72 + colg*8], wA + (size_t)(m0+row)*CIN + k0 + colg*8);
    }
    #pragma unroll
    for (int p = 0; p < 4; ++p) {
      int g = gh + 2*p;
      __attribute__((aligned(16))) __bf16 tmp[8];
      #pragma unroll
      for (int j = 0; j < 8; ++j)
        tmp[j] = (__bf16)Hb[(size_t)(k0 + g*8 + j)*CN + nn];
      *(uint4*)&Bt[nn*72 + g*8] = *(uint4*)tmp;
    }
    __syncthreads();
    #pragma unroll
    for (int kk = 0; kk < 2; ++kk) {
      short8 a[4], bb[2];
      #pragma unroll
      for (int mi = 0; mi < 4; ++mi)
        a[mi] = *(short8*)&At[(mi*16 + l15)*72 + kk*32 + q*8];
      #pragma unroll
      for (int ni = 0; ni < 2; ++ni)
        bb[ni] = *(short8*)&Bt[(w*32 + ni*16 + l15)*72 + kk*32 + q*8];
      #pragma unroll
      for (int mi = 0; mi < 4; ++mi)
        #pragma unroll
        for (int ni = 0; ni < 2; ++ni)
          acc[mi][ni] = MFMA(a[mi], bb[ni], acc[mi][ni]);
    }
    __syncthreads();
  }

  #pragma unroll
  for (int mi = 0; mi < 4; ++mi)
    #pragma unroll
    for (int ni = 0; ni < 2; ++ni)
      #pragma unroll
      for (int r = 0; r < 4; ++r) {
        int m = m0 + mi*16 + q*4 + r;
        int n = w*32 + ni*16 + l15;
        G[((size_t)b*CM + m)*CN + n] = (__bf16)(acc[mi][ni][r] + bA[m]);
      }
}

// ---------------------------------------------------------------------------
// Kernel 4: Z[b][m][s] = sum_n G[b][m][n] * attVT[b][s][n]  -> fp32 output
// LDS-free: fragments straight from global (G is 2 MB, L2-hot; attVT L3-hot).
// No barriers, no shared -> max occupancy, pure latency hiding.
// ---------------------------------------------------------------------------
__global__ __launch_bounds__(256) void z_gemm_kernel(
    const __bf16* __restrict__ G, const __bf16* __restrict__ attVT,
    float* __restrict__ out)
{
  const int m0 = blockIdx.x * 128, s0 = blockIdx.y * 64, b = blockIdx.z;
  const int tid = threadIdx.x, lane = tid & 63, w = tid >> 6;
  const int l15 = lane & 15, q = lane >> 4;

  const __bf16* Gb = G + ((size_t)b*CM + m0)*CN;
  const __bf16* Vb = attVT + ((size_t)b*HW + s0)*CN;

  // B fragments: row s = s0 + w*16 + l15, k-cols (=n) kk*32 + q*8
  short8 bb[4];
  const __bf16* vrow = Vb + (size_t)(w*16 + l15)*CN + q*8;
  #pragma unroll
  for (int kk = 0; kk < 4; ++kk)
    bb[kk] = *(const short8*)(vrow + kk*32);

  f32x4 acc[8] = {};
  #pragma unroll
  for (int kk = 0; kk < 4; ++kk) {
    short8 a[8];
    #pragma unroll
    for (int mi = 0; mi < 8; ++mi)
      a[mi] = *(const short8*)(Gb + (size_t)(mi*16 + l15)*CN + kk*32 + q*8);
    #pragma unroll
    for (int mi = 0; mi < 8; ++mi)
      acc[mi] = MFMA(a[mi], bb[kk], acc[mi]);
  }

  const int s = s0 + w*16 + l15;
  #pragma unroll
  for (int mi = 0; mi < 8; ++mi)
    #pragma unroll
    for (int r = 0; r < 4; ++r) {
      int m = m0 + mi*16 + q*4 + r;
      out[((size_t)b*CM + m)*HW + s] = acc[mi][r];
    }
}

// ---------------------------------------------------------------------------
extern "C" void kernel_launch(void* const* d_in, const int* in_sizes, int n_in,
                              void* d_out, int out_size, void* d_ws, size_t ws_size,
                              hipStream_t stream)
{
  (void)in_sizes; (void)n_in; (void)out_size; (void)ws_size;
  const float* x  = (const float*)d_in[0];
  const float* wA = (const float*)d_in[1];
  const float* bA = (const float*)d_in[2];
  const float* wB = (const float*)d_in[3];
  const float* bB = (const float*)d_in[4];
  const float* wV = (const float*)d_in[5];
  const float* bV = (const float*)d_in[6];
  float* out = (float*)d_out;

  char* ws = (char*)d_ws;
  const size_t szBVB   = (size_t)BATCH*CN*HW*2;     // 12,845,056
  const size_t szAttVT = (size_t)BATCH*HW*CN*2;     // 12,845,056
  const size_t szH     = (size_t)BATCH*CIN*CN*4;    //  4,194,304
  const size_t szBsum  = (size_t)BATCH*CN*4;        //      8,192
  const size_t szG     = (size_t)BATCH*CM*CN*2;     //  2,097,152

  char* p = ws;
  __bf16* BVB   = (__bf16*)p; p += szBVB;
  __bf16* attVT = (__bf16*)p; p += szAttVT;
  float*  H     = (float*)p;  p += szH;
  float*  bsum  = (float*)p;  p += szBsum;   // contiguous with H -> one memset
  __bf16* G     = (__bf16*)p; p += szG;
  __bf16* Wimg  = (__bf16*)p;                // 16384 x 16 B = 262,144

  hipMemsetAsync(H, 0, szH + szBsum, stream);
  prep_w_kernel <<<dim3(64),      256, 0, stream>>>(wB, wV, Wimg);
  conv_bv_kernel<<<dim3(49,16),   256, 0, stream>>>(x, Wimg, bB, bV, BVB, attVT, bsum);
  h_gemm_kernel <<<dim3(8,16,7),  256, 0, stream>>>(x, BVB, bsum, H);
  g_gemm_kernel <<<dim3(8,16),    256, 0, stream>>>(wA, bA, H, G);
  z_gemm_kernel <<<dim3(4,49,16), 256, 0, stream>>>(G, attVT, out);
}

// Round 3
// 283.915 us; speedup vs baseline: 1.1386x; 1.1386x over previous
//
#include <hip/hip_runtime.h>
#include <hip/hip_bf16.h>

#define BATCH 16
#define CIN   512
#define HW    3136
#define CM    512
#define CN    128

typedef short short8 __attribute__((ext_vector_type(8)));
typedef float f32x4  __attribute__((ext_vector_type(4)));

#define MFMA(a,b,c) __builtin_amdgcn_mfma_f32_16x16x32_bf16((a),(b),(c),0,0,0)

// Workgroup barrier WITHOUT the vmcnt(0) drain __syncthreads() emits.
// LDS visibility needs only lgkmcnt(0); global prefetch loads (vmcnt) stay
// in flight across the barrier and are waited at their consuming use.
__device__ __forceinline__ void wg_barrier() {
  asm volatile("s_waitcnt lgkmcnt(0)" ::: "memory");
  __builtin_amdgcn_s_barrier();
  asm volatile("" ::: "memory");
}

// convert 8 consecutive fp32 -> 8 bf16, store as one 16B chunk (LDS or global)
__device__ __forceinline__ void cvt_store8(__bf16* dst, const float* src) {
  const f32x4 a = *(const f32x4*)src;
  const f32x4 b = *(const f32x4*)(src + 4);
  __attribute__((aligned(16))) __bf16 t[8];
  t[0] = (__bf16)a[0]; t[1] = (__bf16)a[1]; t[2] = (__bf16)a[2]; t[3] = (__bf16)a[3];
  t[4] = (__bf16)b[0]; t[5] = (__bf16)b[1]; t[6] = (__bf16)b[2]; t[7] = (__bf16)b[3];
  *(uint4*)dst = *(uint4*)t;
}

// same, from two f32x4 by value (keeps sources in registers)
__device__ __forceinline__ void cvt_store8v(__bf16* dst, f32x4 a, f32x4 b) {
  __attribute__((aligned(16))) __bf16 t[8];
  t[0] = (__bf16)a[0]; t[1] = (__bf16)a[1]; t[2] = (__bf16)a[2]; t[3] = (__bf16)a[3];
  t[4] = (__bf16)b[0]; t[5] = (__bf16)b[1]; t[6] = (__bf16)b[2]; t[7] = (__bf16)b[3];
  *(uint4*)dst = *(uint4*)t;
}

// ---------------------------------------------------------------------------
// Kernel 0: pre-convert (wB|wV) fp32 -> bf16 in MFMA-fragment order.
// Chunk gid = st*2048 + w*512 + mi*128 + kk*64 + lane  (16 B per chunk):
//   holds W[w*64+mi*16+(lane&15)][st*64+kk*32+(lane>>4)*8 .. +8]
// ---------------------------------------------------------------------------
__global__ __launch_bounds__(256) void prep_w_kernel(
    const float* __restrict__ wB, const float* __restrict__ wV,
    __bf16* __restrict__ Wimg)
{
  const int gid  = blockIdx.x * 256 + threadIdx.x;   // 0..16383
  const int lane = gid & 63;
  const int kk   = (gid >> 6) & 1;
  const int mi   = (gid >> 7) & 3;
  const int w    = (gid >> 9) & 3;
  const int st   = (gid >> 11) & 7;
  const int row  = w*64 + mi*16 + (lane & 15);
  const int col  = st*64 + kk*32 + (lane >> 4)*8;
  const float* src = (row < 128) ? (wB + (size_t)row * CIN)
                                 : (wV + (size_t)(row - 128) * CIN);
  cvt_store8(Wimg + (size_t)gid * 8, src + col);
}

// ---------------------------------------------------------------------------
// Kernel 1: conv (wB|wV) @ x + bias, fused V-softmax + B-softmax row sums.
// W fragments in registers (double-buffered, prefetched one step ahead, issued
// FIRST in the step so consuming them next step leaves X loads in flight).
// Xt double-buffered, raw barriers (no vmcnt drain) -> pipeline survives.
// ---------------------------------------------------------------------------
__global__ __launch_bounds__(256) void conv_bv_kernel(
    const float* __restrict__ x,
    const __bf16* __restrict__ Wimg,
    const float* __restrict__ bB, const float* __restrict__ bV,
    __bf16* __restrict__ BVB, __bf16* __restrict__ attVT,
    float* __restrict__ bsum)
{
  const int s0  = blockIdx.x * 64;
  const int b   = blockIdx.y;
  const int tid = threadIdx.x;
  const int lane = tid & 63, w = tid >> 6;
  const int l15  = lane & 15, q = lane >> 4;

  __shared__ __attribute__((aligned(16))) __bf16 Xt[2][64*72]; // 18432 B
  __bf16* T = (__bf16*)Xt;   // epilogue alias [64][136] = 17408 B
  __shared__ float Vm[2][64];
  __shared__ float Vs[2][64];

  f32x4 acc[4][4] = {};
  const float* xb = x + (size_t)b*CIN*HW + s0;
  const int colg = tid & 7;               // s-octet
  const int cl = 2*(tid >> 3);            // even c_local (pair cl, cl+1)
  const int xoff = ((cl >> 3) ^ colg)*8 + (cl & 7);

  const char* wbase = (const char*)Wimg + (size_t)w*8192 + (size_t)lane*16;

  short8 wf[2][8];     // W fragments, double-buffered by step parity
  f32x4 pf[2][4];      // X prefetch, pf[m&1] holds x-cols for step m

#define WLOAD(WB, ST) do { const char* wp_ = wbase + (ST)*32768; \
    wf[WB][0]=*(const short8*)(wp_+0);    wf[WB][1]=*(const short8*)(wp_+1024); \
    wf[WB][2]=*(const short8*)(wp_+2048); wf[WB][3]=*(const short8*)(wp_+3072); \
    wf[WB][4]=*(const short8*)(wp_+4096); wf[WB][5]=*(const short8*)(wp_+5120); \
    wf[WB][6]=*(const short8*)(wp_+6144); wf[WB][7]=*(const short8*)(wp_+7168); } while(0)

#define XLOAD(PB, K0) do { \
    const float* r0_ = xb + (size_t)((K0) + cl)*HW + colg*8; \
    const float* r1_ = r0_ + HW; \
    pf[PB][0] = *(const f32x4*)r0_; pf[PB][1] = *(const f32x4*)(r0_ + 4); \
    pf[PB][2] = *(const f32x4*)r1_; pf[PB][3] = *(const f32x4*)(r1_ + 4); } while(0)

#define XWRITE(BUF, PB) do { \
    _Pragma("unroll") \
    for (int j = 0; j < 8; ++j) { \
      int s_ = colg*8 + j; \
      union { __bf16 h[2]; unsigned int u; } pv_; \
      pv_.h[0] = (__bf16)pf[PB][j>>2][j&3]; \
      pv_.h[1] = (__bf16)pf[PB][2 + (j>>2)][j&3]; \
      *(unsigned int*)&Xt[BUF][s_*72 + xoff] = pv_.u; \
    } } while(0)

  // prologue: X(0), W(0), X(1) in flight; write Xt[0]
  XLOAD(0, 0);
  WLOAD(0, 0);
  XLOAD(1, 64);
  XWRITE(0, 0);
  wg_barrier();

  #pragma unroll
  for (int st = 0; st < 8; ++st) {
    const int cur = st & 1;
    // W prefetch for next step FIRST: oldest in vm queue, so consuming it
    // next step uses a counted wait that leaves the X loads in flight.
    if (st < 7) WLOAD(cur ^ 1, st + 1);

    // kk = 0
    short8 xf0[4];
    #pragma unroll
    for (int si = 0; si < 4; ++si) {
      int s = si*16 + l15;
      int oct = q ^ (si*2 + (l15 >> 3));
      xf0[si] = *(short8*)&Xt[cur][s*72 + oct*8];
    }
    #pragma unroll
    for (int mi = 0; mi < 4; ++mi)
      #pragma unroll
      for (int si = 0; si < 4; ++si)
        acc[mi][si] = MFMA(wf[cur][mi*2], xf0[si], acc[mi][si]);

    if (st < 7) XWRITE(cur ^ 1, (st + 1) & 1);   // stage next tile
    if (st < 6) XLOAD(st & 1, (st + 2) * 64);    // prefetch tile after next

    // kk = 1
    short8 xf1[4];
    #pragma unroll
    for (int si = 0; si < 4; ++si) {
      int s = si*16 + l15;
      int oct = (4 + q) ^ (si*2 + (l15 >> 3));
      xf1[si] = *(short8*)&Xt[cur][s*72 + oct*8];
    }
    #pragma unroll
    for (int mi = 0; mi < 4; ++mi)
      #pragma unroll
      for (int si = 0; si < 4; ++si)
        acc[mi][si] = MFMA(wf[cur][mi*2+1], xf1[si], acc[mi][si]);

    wg_barrier();
  }
#undef WLOAD
#undef XLOAD
#undef XWRITE

  float bias[4][4];
  #pragma unroll
  for (int mi = 0; mi < 4; ++mi)
    #pragma unroll
    for (int r = 0; r < 4; ++r) {
      int nch = w*64 + mi*16 + q*4 + r;
      bias[mi][r] = (nch < CN) ? bB[nch] : bV[nch - CN];
    }

  if (w < 2) {
    // B half: write raw bf16 rows + accumulate per-n sum of exp
    const size_t outb = (size_t)b * CN * HW;
    float psum[4][4] = {};
    #pragma unroll
    for (int mi = 0; mi < 4; ++mi)
      #pragma unroll
      for (int si = 0; si < 4; ++si) {
        int s = s0 + si*16 + l15;
        #pragma unroll
        for (int r = 0; r < 4; ++r) {
          int nch = w*64 + mi*16 + q*4 + r;
          __bf16 bv = (__bf16)(acc[mi][si][r] + bias[mi][r]);
          BVB[outb + (size_t)nch*HW + s] = bv;
          psum[mi][r] += __expf((float)bv);
        }
      }
    #pragma unroll
    for (int mi = 0; mi < 4; ++mi)
      #pragma unroll
      for (int r = 0; r < 4; ++r) {
        float v = psum[mi][r];
        v += __shfl_xor(v, 1); v += __shfl_xor(v, 2);
        v += __shfl_xor(v, 4); v += __shfl_xor(v, 8);
        if (l15 == 0) {
          int nch = w*64 + mi*16 + q*4 + r;
          atomicAdd(&bsum[b*CN + nch], v);
        }
      }
  } else {
    // V half: per-s max over its 128 V channels
    #pragma unroll
    for (int si = 0; si < 4; ++si) {
      float m = -1e30f;
      #pragma unroll
      for (int mi = 0; mi < 4; ++mi)
        #pragma unroll
        for (int r = 0; r < 4; ++r)
          m = fmaxf(m, acc[mi][si][r] + bias[mi][r]);
      m = fmaxf(m, __shfl_xor(m, 16));
      m = fmaxf(m, __shfl_xor(m, 32));
      if (q == 0) Vm[w-2][si*16 + l15] = m;
    }
  }
  wg_barrier();
  if (w >= 2) {
    #pragma unroll
    for (int si = 0; si < 4; ++si) {
      int idx = si*16 + l15;
      float ms = fmaxf(Vm[0][idx], Vm[1][idx]);
      float ssum = 0.f;
      #pragma unroll
      for (int mi = 0; mi < 4; ++mi)
        #pragma unroll
        for (int r = 0; r < 4; ++r) {
          float e = __expf(acc[mi][si][r] + bias[mi][r] - ms);
          acc[mi][si][r] = e;
          ssum += e;
        }
      ssum += __shfl_xor(ssum, 16);
      ssum += __shfl_xor(ssum, 32);
      if (q == 0) Vs[w-2][idx] = ssum;
    }
  }
  wg_barrier();
  if (w >= 2) {
    #pragma unroll
    for (int si = 0; si < 4; ++si) {
      int idx = si*16 + l15;
      float inv = 1.0f / (Vs[0][idx] + Vs[1][idx]);
      #pragma unroll
      for (int mi = 0; mi < 4; ++mi)
        #pragma unroll
        for (int r = 0; r < 4; ++r) {
          int j = (w-2)*64 + mi*16 + q*4 + r;
          T[idx*136 + j] = (__bf16)(acc[mi][si][r] * inv);
        }
    }
  }
  wg_barrier();
  __bf16* dst = attVT + ((size_t)b*HW + s0)*CN;
  #pragma unroll
  for (int k = 0; k < 4; ++k) {
    int chunk = tid + 256*k;
    int row = chunk >> 4, oct = chunk & 15;
    *(uint4*)&dst[(size_t)row*CN + oct*8] = *(uint4*)&T[row*136 + oct*8];
  }
}

// ---------------------------------------------------------------------------
// Kernel 2: H[b][c][n] += sum_s x[b][c][s] * (exp(BVB[n][s]) / bsum[n])
// tile 128c x 128n, split-K=7; one-iter-ahead register prefetch of both
// tiles, riding across BOTH raw barriers (no vmcnt drain).
// ---------------------------------------------------------------------------
__global__ __launch_bounds__(256) void h_gemm_kernel(
    const float* __restrict__ x, const __bf16* __restrict__ BVB,
    const float* __restrict__ bsum, float* __restrict__ H)
{
  const int c0 = blockIdx.x * 128, b = blockIdx.y, kc = blockIdx.z;
  const int tid = threadIdx.x, lane = tid & 63, w = tid >> 6;
  const int l15 = lane & 15, q = lane >> 4;

  __shared__ __attribute__((aligned(16))) __bf16 At[128*72];  // x tile [c][s]
  __shared__ __attribute__((aligned(16))) __bf16 Bt[128*72];  // attB tile [n][s]
  f32x4 acc[8][2] = {};

  const float* xb = x + ((size_t)b*CIN + c0)*HW;
  const __bf16* ab = BVB + (size_t)b*CN*HW;
  const float* bsb = bsum + b*CN;
  const int colg = tid & 7, row0 = tid >> 3;

  float irow[4];
  #pragma unroll
  for (int p = 0; p < 4; ++p) irow[p] = 1.0f / bsb[row0 + 32*p];

  f32x4 px[4][2];
  uint4 pB[4];
#define HLOAD(K0) do { \
    _Pragma("unroll") \
    for (int p = 0; p < 4; ++p) { \
      const float* s_ = xb + (size_t)(row0 + 32*p)*HW + (K0) + colg*8; \
      px[p][0] = *(const f32x4*)s_; px[p][1] = *(const f32x4*)(s_ + 4); \
    } \
    _Pragma("unroll") \
    for (int p = 0; p < 4; ++p) \
      pB[p] = *(const uint4*)(ab + (size_t)(row0 + 32*p)*HW + (K0) + colg*8); \
  } while(0)

  const int kbase = kc * 448;
  HLOAD(kbase);

  for (int ki = 0; ki < 7; ++ki) {
    // consume prefetched tiles into LDS (vmcnt waits are fine-grained here)
    #pragma unroll
    for (int p = 0; p < 4; ++p)
      cvt_store8v(&At[(row0 + 32*p)*72 + colg*8], px[p][0], px[p][1]);
    #pragma unroll
    for (int p = 0; p < 4; ++p) {
      const __bf16* v = (const __bf16*)&pB[p];
      __attribute__((aligned(16))) __bf16 t[8];
      #pragma unroll
      for (int j = 0; j < 8; ++j)
        t[j] = (__bf16)(__expf((float)v[j]) * irow[p]);
      *(uint4*)&Bt[(row0 + 32*p)*72 + colg*8] = *(uint4*)t;
    }
    if (ki < 6) HLOAD(kbase + (ki + 1)*64);   // stays in flight across barriers
    wg_barrier();
    #pragma unroll
    for (int kk = 0; kk < 2; ++kk) {
      short8 a[8], bb[2];
      #pragma unroll
      for (int mi = 0; mi < 8; ++mi)
        a[mi] = *(short8*)&At[(mi*16 + l15)*72 + kk*32 + q*8];
      #pragma unroll
      for (int ni = 0; ni < 2; ++ni)
        bb[ni] = *(short8*)&Bt[(w*32 + ni*16 + l15)*72 + kk*32 + q*8];
      #pragma unroll
      for (int mi = 0; mi < 8; ++mi)
        #pragma unroll
        for (int ni = 0; ni < 2; ++ni)
          acc[mi][ni] = MFMA(a[mi], bb[ni], acc[mi][ni]);
    }
    wg_barrier();
  }
#undef HLOAD

  float* Hb = H + (size_t)b*CIN*CN;
  #pragma unroll
  for (int mi = 0; mi < 8; ++mi)
    #pragma unroll
    for (int ni = 0; ni < 2; ++ni)
      #pragma unroll
      for (int r = 0; r < 4; ++r) {
        int c = c0 + mi*16 + q*4 + r;
        int n = w*32 + ni*16 + l15;
        atomicAdd(&Hb[c*CN + n], acc[mi][ni][r]);
      }
}

// ---------------------------------------------------------------------------
// Kernel 3: G[b] = wA @ H[b] + bA  (M=512 in 64-tiles, N=128, K=512) -> bf16
// ---------------------------------------------------------------------------
__global__ __launch_bounds__(256) void g_gemm_kernel(
    const float* __restrict__ wA, const float* __restrict__ bA,
    const float* __restrict__ H, __bf16* __restrict__ G)
{
  const int m0 = blockIdx.x * 64, b = blockIdx.y;
  const int tid = threadIdx.x, lane = tid & 63, w = tid >> 6;
  const int l15 = lane & 15, q = lane >> 4;

  __shared__ __attribute__((aligned(16))) __bf16 At[64*72];
  __shared__ __attribute__((aligned(16))) __bf16 Bt[128*72];
  f32x4 acc[4][2] = {};

  const float* Hb = H + (size_t)b*CIN*CN;
  const int colg = tid & 7, row0 = tid >> 3;
  const int nn = tid & 127, gh = tid >> 7;

  for (int k0 = 0; k0 < CIN; k0 += 64) {
    #pragma unroll
    for (int p = 0; p < 2; ++p) {
      int row = row0 + 32*p;
      cvt_store8(&At[row*72 + colg*8], wA + (size_t)(m0+row)*CIN + k0 + colg*8);
    }
    #pragma unroll
    for (int p = 0; p < 4; ++p) {
      int g = gh + 2*p;
      __attribute__((aligned(16))) __bf16 tmp[8];
      #pragma unroll
      for (int j = 0; j < 8; ++j)
        tmp[j] = (__bf16)Hb[(size_t)(k0 + g*8 + j)*CN + nn];
      *(uint4*)&Bt[nn*72 + g*8] = *(uint4*)tmp;
    }
    wg_barrier();
    #pragma unroll
    for (int kk = 0; kk < 2; ++kk) {
      short8 a[4], bb[2];
      #pragma unroll
      for (int mi = 0; mi < 4; ++mi)
        a[mi] = *(short8*)&At[(mi*16 + l15)*72 + kk*32 + q*8];
      #pragma unroll
      for (int ni = 0; ni < 2; ++ni)
        bb[ni] = *(short8*)&Bt[(w*32 + ni*16 + l15)*72 + kk*32 + q*8];
      #pragma unroll
      for (int mi = 0; mi < 4; ++mi)
        #pragma unroll
        for (int ni = 0; ni < 2; ++ni)
          acc[mi][ni] = MFMA(a[mi], bb[ni], acc[mi][ni]);
    }
    wg_barrier();
  }

  #pragma unroll
  for (int mi = 0; mi < 4; ++mi)
    #pragma unroll
    for (int ni = 0; ni < 2; ++ni)
      #pragma unroll
      for (int r = 0; r < 4; ++r) {
        int m = m0 + mi*16 + q*4 + r;
        int n = w*32 + ni*16 + l15;
        G[((size_t)b*CM + m)*CN + n] = (__bf16)(acc[mi][ni][r] + bA[m]);
      }
}

// ---------------------------------------------------------------------------
// Kernel 4: Z[b][m][s] = sum_n G[b][m][n] * attVT[b][s][n]  -> fp32 output
// (round-0 LDS version: stage both tiles, one barrier, 32 MFMA/wave)
// ---------------------------------------------------------------------------
__global__ __launch_bounds__(256) void z_gemm_kernel(
    const __bf16* __restrict__ G, const __bf16* __restrict__ attVT,
    float* __restrict__ out)
{
  const int m0 = blockIdx.x * 128, s0 = blockIdx.y * 64, b = blockIdx.z;
  const int tid = threadIdx.x, lane = tid & 63, w = tid >> 6;
  const int l15 = lane & 15, q = lane >> 4;

  __shared__ __attribute__((aligned(16))) __bf16 At[128*136];
  __shared__ __attribute__((aligned(16))) __bf16 Bt[64*136];

  const __bf16* Gb = G + ((size_t)b*CM + m0)*CN;
  const __bf16* Vb = attVT + ((size_t)b*HW + s0)*CN;
  const int g = tid & 15, r0 = tid >> 4;
  #pragma unroll
  for (int p = 0; p < 8; ++p) {
    int row = r0 + 16*p;
    *(uint4*)&At[row*136 + g*8] = *(const uint4*)(Gb + (size_t)row*CN + g*8);
  }
  #pragma unroll
  for (int p = 0; p < 4; ++p) {
    int row = r0 + 16*p;
    *(uint4*)&Bt[row*136 + g*8] = *(const uint4*)(Vb + (size_t)row*CN + g*8);
  }
  wg_barrier();

  f32x4 acc[8] = {};
  #pragma unroll
  for (int kk = 0; kk < 4; ++kk) {
    short8 bb = *(short8*)&Bt[(w*16 + l15)*136 + kk*32 + q*8];
    #pragma unroll
    for (int mi = 0; mi < 8; ++mi) {
      short8 a = *(short8*)&At[(mi*16 + l15)*136 + kk*32 + q*8];
      acc[mi] = MFMA(a, bb, acc[mi]);
    }
  }

  const int s = s0 + w*16 + l15;
  #pragma unroll
  for (int mi = 0; mi < 8; ++mi)
    #pragma unroll
    for (int r = 0; r < 4; ++r) {
      int m = m0 + mi*16 + q*4 + r;
      out[((size_t)b*CM + m)*HW + s] = acc[mi][r];
    }
}

// ---------------------------------------------------------------------------
extern "C" void kernel_launch(void* const* d_in, const int* in_sizes, int n_in,
                              void* d_out, int out_size, void* d_ws, size_t ws_size,
                              hipStream_t stream)
{
  (void)in_sizes; (void)n_in; (void)out_size; (void)ws_size;
  const float* x  = (const float*)d_in[0];
  const float* wA = (const float*)d_in[1];
  const float* bA = (const float*)d_in[2];
  const float* wB = (const float*)d_in[3];
  const float* bB = (const float*)d_in[4];
  const float* wV = (const float*)d_in[5];
  const float* bV = (const float*)d_in[6];
  float* out = (float*)d_out;

  char* ws = (char*)d_ws;
  const size_t szBVB   = (size_t)BATCH*CN*HW*2;     // 12,845,056
  const size_t szAttVT = (size_t)BATCH*HW*CN*2;     // 12,845,056
  const size_t szH     = (size_t)BATCH*CIN*CN*4;    //  4,194,304
  const size_t szBsum  = (size_t)BATCH*CN*4;        //      8,192
  const size_t szG     = (size_t)BATCH*CM*CN*2;     //  2,097,152

  char* p = ws;
  __bf16* BVB   = (__bf16*)p; p += szBVB;
  __bf16* attVT = (__bf16*)p; p += szAttVT;
  float*  H     = (float*)p;  p += szH;
  float*  bsum  = (float*)p;  p += szBsum;   // contiguous with H -> one memset
  __bf16* G     = (__bf16*)p; p += szG;
  __bf16* Wimg  = (__bf16*)p;                // 16384 x 16 B = 262,144

  hipMemsetAsync(H, 0, szH + szBsum, stream);
  prep_w_kernel <<<dim3(64),      256, 0, stream>>>(wB, wV, Wimg);
  conv_bv_kernel<<<dim3(49,16),   256, 0, stream>>>(x, Wimg, bB, bV, BVB, attVT, bsum);
  h_gemm_kernel <<<dim3(4,16,7),  256, 0, stream>>>(x, BVB, bsum, H);
  g_gemm_kernel <<<dim3(8,16),    256, 0, stream>>>(wA, bA, H, G);
  z_gemm_kernel <<<dim3(4,49,16), 256, 0, stream>>>(G, attVT, out);
}